// Round 3
// baseline (165.442 us; speedup 1.0000x reference)
//
#include <hip/hip_runtime.h>

#define T_LEN 2048
#define NMODE 8
#define NPP   17   // 8 tau + 9 g

// ---------------------------------------------------------------------------
// Fused scan phase. Computes Prony coefficients inline from raw inputs
// (transcendentals are cheap; saves the AC round-trip through HBM).
// Thread = (b, c, e). L steps per chunk, NC = T_LEN/L chunks.
//   PHASE3=false: from zero state, emit R[b,c,e,m] (chunk result) and
//                 P[b,c,m] (per-mode product of A; e==0 writes).
//   PHASE3=true : R holds per-chunk initial states Z; rerun and write outputs.
// All pp/t/Se rows for the chunk are loaded upfront (independent addresses,
// single latency exposure), then the recurrence is pure VALU.
// ---------------------------------------------------------------------------
template <int L, bool PHASE3>
__global__ __launch_bounds__(256)
void scan_fused(const float* __restrict__ Se,   // [B,T,3,3]
                const float* __restrict__ tt,   // [B,T]
                const float* __restrict__ pp,   // [B,T,17]
                float* __restrict__ R,          // [B,NC,9,8]
                float* __restrict__ P,          // [B,NC,8]
                float* __restrict__ out,        // [3,B,T,3,3]
                int B) {
    constexpr int NC = T_LEN / L;
    int tid = blockIdx.x * blockDim.x + threadIdx.x;
    int total = B * NC * 9;
    if (tid >= total) return;
    int e  = tid % 9;
    int bc = tid / 9;
    int c  = bc % NC;
    int b  = bc / NC;
    int t0 = c * L;

    // ---- upfront loads: rows max(t0-1,0) .. t0+L-1 ----
    float raw[L + 1][NPP];   // pp rows (r=0 is the "previous" row)
    float tv[L + 1];         // t per row
    float sv[L + 1];         // Se[...,e] per row
    #pragma unroll
    for (int r = 0; r <= L; ++r) {
        int trow = t0 + r - 1; if (trow < 0) trow = 0;
        size_t row = (size_t)b * T_LEN + trow;
        const float* p = pp + row * NPP;
        #pragma unroll
        for (int k = 0; k < NPP; ++k) raw[r][k] = p[k];
        tv[r] = tt[row];
        sv[r] = Se[row * 9 + (size_t)e];
    }
    if (t0 == 0) {               // reference init: t_p=-t[:,1], S_p=0
        tv[0] = -tt[(size_t)b * T_LEN + 1];
        sv[0] = 0.f;
    }

    // per-row 1/sum(g)
    float inv[L + 1];
    #pragma unroll
    for (int r = 0; r <= L; ++r) {
        float s = 0.f;
        #pragma unroll
        for (int k = 8; k < NPP; ++k) s += raw[r][k];
        inv[r] = __builtin_amdgcn_rcpf(s);
    }

    size_t rbase = ((size_t)(b * NC + c) * 9 + (size_t)e) * NMODE;

    float Q[NMODE], Pp[NMODE];
    if (PHASE3) {
        const float4* rz = (const float4*)(R + rbase);
        float4 z0 = rz[0], z1 = rz[1];
        Q[0]=z0.x; Q[1]=z0.y; Q[2]=z0.z; Q[3]=z0.w;
        Q[4]=z1.x; Q[5]=z1.y; Q[6]=z1.z; Q[7]=z1.w;
    } else {
        #pragma unroll
        for (int m = 0; m < NMODE; ++m) { Q[m] = 0.f; Pp[m] = 1.0f; }
    }

    const size_t nOut = (size_t)B * T_LEN * 9;

    #pragma unroll
    for (int s = 0; s < L; ++s) {
        const int rc = s + 1, rp = s;
        float mhdt = -0.5f * (tv[rc] - tv[rp]);
        float dS   = sv[rc] - sv[rp];
        float qsum = 0.f;
        #pragma unroll
        for (int m = 0; m < NMODE; ++m) {
            float tau_b = 0.5f * (raw[rc][m] + raw[rp][m]);
            float g_b   = 0.5f * (raw[rc][9 + m] * inv[rc]
                                + raw[rp][9 + m] * inv[rp]);
            float ee    = __expf(mhdt * __builtin_amdgcn_rcpf(tau_b));
            float A     = ee * ee;
            Q[m] = A * Q[m] + (ee * g_b) * dS;
            if (!PHASE3) Pp[m] *= A;
            else         qsum  += Q[m];
        }
        if (PHASE3) {
            size_t sidx = ((size_t)b * T_LEN + t0 + s) * 9 + (size_t)e;
            float sinf = (raw[rc][8] * inv[rc]) * sv[rc];
            out[sidx]            = sinf + qsum;  // S
            out[nOut + sidx]     = sinf;         // S_infy
            out[2 * nOut + sidx] = qsum;         // Q_sum
        }
    }

    if (!PHASE3) {
        float4* rz = (float4*)(R + rbase);
        rz[0] = make_float4(Q[0], Q[1], Q[2], Q[3]);
        rz[1] = make_float4(Q[4], Q[5], Q[6], Q[7]);
        if (e == 0) {
            float4* pz = (float4*)(P + (size_t)(b * NC + c) * NMODE);
            pz[0] = make_float4(Pp[0], Pp[1], Pp[2], Pp[3]);
            pz[1] = make_float4(Pp[4], Pp[5], Pp[6], Pp[7]);
        }
    }
}

// ---------------------------------------------------------------------------
// Wave-parallel inter-chunk scan. One wave per (b,e,m) sequence of NC chunks.
// Lane l serially composes its K=NC/64 chunk transforms, 6-step shfl_up
// butterfly composes across lanes, then lanes write per-chunk entry states Z
// back into R. Affine compose (applied-first on the right):
//   (p2,r2)∘(p1,r1) = (p2*p1, p2*r1 + r2)
// ---------------------------------------------------------------------------
template <int K>
__global__ __launch_bounds__(256)
void chunk_scan_wave(float* __restrict__ R, const float* __restrict__ P,
                     int B) {
    constexpr int NC = K * 64;
    int gtid = blockIdx.x * blockDim.x + threadIdx.x;
    int wid  = gtid >> 6;
    int lane = gtid & 63;
    int total = B * 9 * NMODE;
    if (wid >= total) return;
    int m = wid % NMODE;
    int e = (wid / NMODE) % 9;
    int b = wid / (9 * NMODE);

    float pk[K], rk[K];
    float pa = 1.f, ra = 0.f;
    #pragma unroll
    for (int k = 0; k < K; ++k) {
        int c = lane * K + k;
        rk[k] = R[((size_t)(b * NC + c) * 9 + (size_t)e) * NMODE + m];
        pk[k] = P[(size_t)(b * NC + c) * NMODE + m];
        ra = pk[k] * ra + rk[k];
        pa = pk[k] * pa;
    }
    #pragma unroll
    for (int d = 1; d < 64; d <<= 1) {
        float plo = __shfl_up(pa, d);
        float rlo = __shfl_up(ra, d);
        if (lane >= d) {
            ra = pa * rlo + ra;
            pa = pa * plo;
        }
    }
    float z = __shfl_up(ra, 1);
    if (lane == 0) z = 0.f;
    #pragma unroll
    for (int k = 0; k < K; ++k) {
        int c = lane * K + k;
        R[((size_t)(b * NC + c) * 9 + (size_t)e) * NMODE + m] = z;
        z = pk[k] * z + rk[k];
    }
}

// ---------------------------------------------------------------------------
template <int L>
static void run_pipeline(const float* Se, const float* tt, const float* pp,
                         float* out, float* ws, int B, hipStream_t stream) {
    constexpr int NC = T_LEN / L;
    constexpr int K  = NC / 64;
    float* R = ws;
    float* P = R + (size_t)B * NC * 9 * NMODE;

    dim3 blk(256);
    int tot1  = B * NC * 9;
    int grid1 = (tot1 + 255) / 256;
    int tot2  = B * 9 * NMODE * 64;          // one wave per sequence
    int grid2 = (tot2 + 255) / 256;

    scan_fused<L, false><<<grid1, blk, 0, stream>>>(Se, tt, pp, R, P, nullptr, B);
    chunk_scan_wave<K><<<grid2, blk, 0, stream>>>(R, P, B);
    scan_fused<L, true><<<grid1, blk, 0, stream>>>(Se, tt, pp, R, P, out, B);
}

extern "C" void kernel_launch(void* const* d_in, const int* in_sizes, int n_in,
                              void* d_out, int out_size, void* d_ws, size_t ws_size,
                              hipStream_t stream) {
    const float* Se = (const float*)d_in[0];
    const float* tt = (const float*)d_in[1];
    const float* pp = (const float*)d_in[2];
    float* out = (float*)d_out;
    float* ws  = (float*)d_ws;

    int B = in_sizes[1] / T_LEN;

    auto need = [&](int NC) {
        return ((size_t)B * NC * 9 * NMODE + (size_t)B * NC * NMODE) * sizeof(float);
    };

    if (need(T_LEN / 4) <= ws_size) {
        run_pipeline<4>(Se, tt, pp, out, ws, B, stream);     // NC=512
    } else if (need(T_LEN / 8) <= ws_size) {
        run_pipeline<8>(Se, tt, pp, out, ws, B, stream);     // NC=256
    } else {
        run_pipeline<16>(Se, tt, pp, out, ws, B, stream);    // NC=128
    }
}

// Round 4
// 120.633 us; speedup vs baseline: 1.3714x; 1.3714x over previous
//
#include <hip/hip_runtime.h>

#define T_LEN 2048
#define NMODE 8
#define NPP   17   // 8 tau + 9 g

// ---------------------------------------------------------------------------
// Fused scan phase, streaming (low register pressure).
// Thread = (b, c, e); L steps per chunk; NC = T_LEN/L.
//   PHASE3=false: from zero state, emit R[b,e,c,m] and P[b,c,m] (e==0 only).
//   PHASE3=true : R holds per-chunk entry states Z; rerun, write outputs.
// R layout [b,e,c,m]: ((b*9+e)*NC + c)*8 + m  -> 32B-aligned, contiguous in m,
// consecutive chunks contiguous (coalesced for the inter-chunk scan kernel).
// ---------------------------------------------------------------------------
template <int L, bool PHASE3>
__global__ __launch_bounds__(256)
void scan_fused(const float* __restrict__ Se,   // [B,T,3,3]
                const float* __restrict__ tt,   // [B,T]
                const float* __restrict__ pp,   // [B,T,17]
                float* __restrict__ R,          // [B,9,NC,8]
                float* __restrict__ P,          // [B,NC,8]
                float* __restrict__ out,        // [3,B,T,3,3]
                int B) {
    constexpr int NC = T_LEN / L;
    int tid = blockIdx.x * blockDim.x + threadIdx.x;
    int total = B * NC * 9;
    if (tid >= total) return;
    int e  = tid % 9;
    int bc = tid / 9;
    int c  = bc % NC;
    int b  = bc / NC;
    int t0 = c * L;

    // ---- previous-row state ----
    float tau_p[NMODE], g_p[NMODE];
    float inv_p, t_p, S_p;
    {
        int prow = (t0 == 0) ? 0 : (t0 - 1);
        size_t row = (size_t)b * T_LEN + prow;
        const float* p = pp + row * NPP;
        float gsum = 0.f;
        #pragma unroll
        for (int m = 0; m < NMODE; ++m) tau_p[m] = p[m];
        float g8 = p[8];
        #pragma unroll
        for (int m = 0; m < NMODE; ++m) g_p[m] = p[9 + m];
        gsum = g8;
        #pragma unroll
        for (int m = 0; m < NMODE; ++m) gsum += g_p[m];
        inv_p = __builtin_amdgcn_rcpf(gsum);
        t_p = (t0 == 0) ? -tt[(size_t)b * T_LEN + 1] : tt[row];
        S_p = (t0 == 0) ? 0.f : Se[row * 9 + (size_t)e];
    }

    size_t rbase = ((size_t)(b * 9 + e) * NC + (size_t)c) * NMODE;

    float Q[NMODE], Pp[NMODE];
    if (PHASE3) {
        const float4* rz = (const float4*)(R + rbase);
        float4 z0 = rz[0], z1 = rz[1];
        Q[0]=z0.x; Q[1]=z0.y; Q[2]=z0.z; Q[3]=z0.w;
        Q[4]=z1.x; Q[5]=z1.y; Q[6]=z1.z; Q[7]=z1.w;
    } else {
        #pragma unroll
        for (int m = 0; m < NMODE; ++m) { Q[m] = 0.f; Pp[m] = 1.0f; }
    }

    const size_t nOut = (size_t)B * T_LEN * 9;

    #pragma unroll 2
    for (int s = 0; s < L; ++s) {
        size_t row = (size_t)b * T_LEN + (t0 + s);
        const float* p = pp + row * NPP;

        float tau_c[NMODE], g_c[NMODE];
        #pragma unroll
        for (int m = 0; m < NMODE; ++m) tau_c[m] = p[m];
        float g8 = p[8];
        #pragma unroll
        for (int m = 0; m < NMODE; ++m) g_c[m] = p[9 + m];
        float t_c = tt[row];
        float S_c = Se[row * 9 + (size_t)e];

        float gsum = g8;
        #pragma unroll
        for (int m = 0; m < NMODE; ++m) gsum += g_c[m];
        float inv_c = __builtin_amdgcn_rcpf(gsum);

        float mhdt = -0.5f * (t_c - t_p);
        float dS   = S_c - S_p;
        float qsum = 0.f;

        #pragma unroll
        for (int m = 0; m < NMODE; ++m) {
            float tau_b = 0.5f * (tau_c[m] + tau_p[m]);
            float g_b   = 0.5f * (g_c[m] * inv_c + g_p[m] * inv_p);
            float ee    = __expf(mhdt * __builtin_amdgcn_rcpf(tau_b));
            float A     = ee * ee;
            Q[m] = A * Q[m] + (ee * g_b) * dS;
            if (!PHASE3) Pp[m] *= A;
            else         qsum  += Q[m];
            tau_p[m] = tau_c[m];
            g_p[m]   = g_c[m];
        }
        inv_p = inv_c;
        t_p   = t_c;
        S_p   = S_c;

        if (PHASE3) {
            size_t sidx = row * 9 + (size_t)e;
            float sinf = (g8 * inv_c) * S_c;
            out[sidx]            = sinf + qsum;  // S
            out[nOut + sidx]     = sinf;         // S_infy
            out[2 * nOut + sidx] = qsum;         // Q_sum
        }
    }

    if (!PHASE3) {
        float4* rz = (float4*)(R + rbase);
        rz[0] = make_float4(Q[0], Q[1], Q[2], Q[3]);
        rz[1] = make_float4(Q[4], Q[5], Q[6], Q[7]);
        if (e == 0) {
            float4* pz = (float4*)(P + ((size_t)b * NC + (size_t)c) * NMODE);
            pz[0] = make_float4(Pp[0], Pp[1], Pp[2], Pp[3]);
            pz[1] = make_float4(Pp[4], Pp[5], Pp[6], Pp[7]);
        }
    }
}

// ---------------------------------------------------------------------------
// Inter-chunk scan: ONE WAVE per (b,e). Lane l owns K consecutive chunks,
// loading each chunk's 8-float R (and shared 8-float P) fully coalesced
// (contiguous 32B per chunk, 256B per lane). Lane-local affine compose,
// 6-step shfl_up butterfly over the 16-float (P,R) state, exclusive shift,
// then replay writes per-chunk entry states Z back into R.
// Compose (chunk c applied after prefix): Pnet = Pc*Ppre, Rnet = Pc*Rpre + Rc.
// ---------------------------------------------------------------------------
template <int K>
__global__ __launch_bounds__(256)
void chunk_scan_wave(float* __restrict__ R, const float* __restrict__ P,
                     int B) {
    constexpr int NC = K * 64;
    int gtid = blockIdx.x * blockDim.x + threadIdx.x;
    int wid  = gtid >> 6;
    int lane = gtid & 63;
    if (wid >= B * 9) return;
    int e = wid % 9;
    int b = wid / 9;

    float* rp       = R + ((size_t)(b * 9 + e) * NC) * NMODE;
    const float* pq = P + ((size_t)b * NC) * NMODE;

    float pk[K][NMODE], rk[K][NMODE];
    float pa[NMODE], ra[NMODE];
    #pragma unroll
    for (int m = 0; m < NMODE; ++m) { pa[m] = 1.f; ra[m] = 0.f; }

    #pragma unroll
    for (int k = 0; k < K; ++k) {
        int c = lane * K + k;
        const float4* rv = (const float4*)(rp + (size_t)c * NMODE);
        const float4* pv = (const float4*)(pq + (size_t)c * NMODE);
        float4 r0 = rv[0], r1 = rv[1], p0 = pv[0], p1 = pv[1];
        rk[k][0]=r0.x; rk[k][1]=r0.y; rk[k][2]=r0.z; rk[k][3]=r0.w;
        rk[k][4]=r1.x; rk[k][5]=r1.y; rk[k][6]=r1.z; rk[k][7]=r1.w;
        pk[k][0]=p0.x; pk[k][1]=p0.y; pk[k][2]=p0.z; pk[k][3]=p0.w;
        pk[k][4]=p1.x; pk[k][5]=p1.y; pk[k][6]=p1.z; pk[k][7]=p1.w;
        #pragma unroll
        for (int m = 0; m < NMODE; ++m) {
            ra[m] = pk[k][m] * ra[m] + rk[k][m];
            pa[m] = pk[k][m] * pa[m];
        }
    }

    #pragma unroll
    for (int d = 1; d < 64; d <<= 1) {
        #pragma unroll
        for (int m = 0; m < NMODE; ++m) {
            float plo = __shfl_up(pa[m], d);
            float rlo = __shfl_up(ra[m], d);
            if (lane >= d) {
                ra[m] = pa[m] * rlo + ra[m];
                pa[m] = pa[m] * plo;
            }
        }
    }

    float z[NMODE];
    #pragma unroll
    for (int m = 0; m < NMODE; ++m) {
        float zz = __shfl_up(ra[m], 1);
        z[m] = (lane == 0) ? 0.f : zz;
    }

    #pragma unroll
    for (int k = 0; k < K; ++k) {
        int c = lane * K + k;
        float4* rv = (float4*)(rp + (size_t)c * NMODE);
        rv[0] = make_float4(z[0], z[1], z[2], z[3]);
        rv[1] = make_float4(z[4], z[5], z[6], z[7]);
        #pragma unroll
        for (int m = 0; m < NMODE; ++m)
            z[m] = pk[k][m] * z[m] + rk[k][m];
    }
}

// ---------------------------------------------------------------------------
template <int L>
static void run_pipeline(const float* Se, const float* tt, const float* pp,
                         float* out, float* ws, int B, hipStream_t stream) {
    constexpr int NC = T_LEN / L;
    constexpr int K  = NC / 64;
    float* R = ws;
    float* P = R + (size_t)B * 9 * NC * NMODE;

    dim3 blk(256);
    int tot1  = B * NC * 9;
    int grid1 = (tot1 + 255) / 256;
    int tot2  = B * 9 * 64;                 // one wave per (b,e)
    int grid2 = (tot2 + 255) / 256;

    scan_fused<L, false><<<grid1, blk, 0, stream>>>(Se, tt, pp, R, P, nullptr, B);
    chunk_scan_wave<K><<<grid2, blk, 0, stream>>>(R, P, B);
    scan_fused<L, true><<<grid1, blk, 0, stream>>>(Se, tt, pp, R, P, out, B);
}

extern "C" void kernel_launch(void* const* d_in, const int* in_sizes, int n_in,
                              void* d_out, int out_size, void* d_ws, size_t ws_size,
                              hipStream_t stream) {
    const float* Se = (const float*)d_in[0];
    const float* tt = (const float*)d_in[1];
    const float* pp = (const float*)d_in[2];
    float* out = (float*)d_out;
    float* ws  = (float*)d_ws;

    int B = in_sizes[1] / T_LEN;

    auto need = [&](int NC) {
        return ((size_t)B * 9 * NC * NMODE + (size_t)B * NC * NMODE) * sizeof(float);
    };

    if (need(T_LEN / 8) <= ws_size) {
        run_pipeline<8>(Se, tt, pp, out, ws, B, stream);     // NC=256, K=4
    } else if (need(T_LEN / 16) <= ws_size) {
        run_pipeline<16>(Se, tt, pp, out, ws, B, stream);    // NC=128, K=2
    } else {
        run_pipeline<32>(Se, tt, pp, out, ws, B, stream);    // NC=64,  K=1
    }
}